// Round 9
// baseline (983.807 us; speedup 1.0000x reference)
//
#include <hip/hip_runtime.h>
#include <hip/hip_bf16.h>

// Decomposable attention, bf16-MFMA pipeline, chunked (Bh per side per chunk).
// R9: 32x32x16 MFMA (halved MFMA instr count + frag regs, same LDS traffic);
// BN-templated block tile: BN=64 variant for e1/att/h (2x blocks for the
// latency-bound small-N shapes).

using f32x4 = __attribute__((ext_vector_type(4))) float;
using f32x16 = __attribute__((ext_vector_type(16))) float;
using s16x8 = __attribute__((ext_vector_type(8))) short;

__device__ __forceinline__ void gload_lds16(const short* g, short* l) {
  __builtin_amdgcn_global_load_lds(
      (const __attribute__((address_space(1))) unsigned int*)g,
      (__attribute__((address_space(3))) unsigned int*)l, 16, 0, 0);
}

// ---------------- GEMM: C[M,N] = A[M,K] * B[N,K]^T (+bias, relu) ----------------
// grid = (N/BN, M/128, batch), block = 256. K % 64 == 0.
// LDS: [rows][64] bf16; row r chunk c (16B) at slot c ^ (r&7) (conflict-free).
// MFMA 32x32x16: A/B frag = row lane&31, k = (lane>>5)*8+i; C/D per m74/m101.
// SUML: row-sum per 256-row batch into float Cv; sC = split (BN=128 only).
// CONCAT: att epilogue fills right concat half (coalesced tile sweep).
template <int BN, bool RELU, bool OUT_BF16, bool HAS_BIAS, bool SUML,
          bool CONCAT>
__global__ __launch_bounds__(256, 4) void gemm_nt(
    const short* __restrict__ A, const short* __restrict__ B,
    const float* __restrict__ bias, void* __restrict__ Cv, int K, int lda,
    int ldb, int ldc, long sA, long sB, long sC, const float* __restrict__ cs1,
    const float* __restrict__ cs2, int cBh) {
  constexpr int NH = BN / 64;  // n-frags per wave
  __shared__ __align__(16) short As[128 * 64];
  __shared__ __align__(16) short Bs[BN * 64];
  const int t = threadIdx.x;
  const int lane = t & 63;
  const int wave = t >> 6;

  // XCD-aware swizzle (flat%8 ~ XCD): contiguous tile range per XCD.
  unsigned flat = (blockIdx.z * gridDim.y + blockIdx.y) * gridDim.x + blockIdx.x;
  const unsigned total = gridDim.x * gridDim.y * gridDim.z;
  unsigned bx = blockIdx.x, by = blockIdx.y, bz = blockIdx.z;
  if ((total & 7u) == 0) {
    unsigned nf = (flat & 7u) * (total >> 3) + (flat >> 3);
    bx = nf % gridDim.x;
    unsigned rest = nf / gridDim.x;
    by = rest % gridDim.y;
    bz = rest / gridDim.y;
  }
  const int m0 = by * 128;
  const int n0 = bx * BN;
  const long zb = bz;

  // staging: thread t -> row q*32 + (t>>3), chunk slot (t&7); fetches global
  // chunk (t&7)^(row&7) so LDS slot c holds swizzled content.
  const int srow = t >> 3;
  const int schunk = ((t & 7) ^ (srow & 7)) * 8;
  const short* ag = A + zb * sA + (long)(m0 + srow) * lda + schunk;
  const short* bg = B + zb * sB + (long)(n0 + srow) * ldb + schunk;
  const long a32 = (long)32 * lda, b32 = (long)32 * ldb;
  short* AsW = As + wave * 512;
  short* BsW = Bs + wave * 512;

  const int ln = lane & 31;
  const int hi = lane >> 5;  // k-subgroup (0/1)
  int abase[2], asw[2], bbase[NH], bsw[NH];
#pragma unroll
  for (int i = 0; i < 2; ++i) {
    const int ra = (wave >> 1) * 64 + i * 32 + ln;
    abase[i] = ra * 64;
    asw[i] = ra & 7;
  }
#pragma unroll
  for (int j = 0; j < NH; ++j) {
    const int rb = (wave & 1) * (BN / 2) + j * 32 + ln;
    bbase[j] = rb * 64;
    bsw[j] = rb & 7;
  }

  f32x16 acc[2][NH] = {};

  for (int it = K >> 6; it > 0; --it) {
    gload_lds16(ag, AsW);
    gload_lds16(ag + a32, AsW + 2048);
    gload_lds16(ag + 2 * a32, AsW + 4096);
    gload_lds16(ag + 3 * a32, AsW + 6144);
#pragma unroll
    for (int q = 0; q < BN / 32; ++q)
      gload_lds16(bg + q * b32, BsW + q * 2048);
    ag += 64;
    bg += 64;
    __syncthreads();
#pragma unroll
    for (int s = 0; s < 4; ++s) {
      const int c = (s << 1) | hi;  // 16B chunk index for this k-step
      s16x8 af[2], bfv[NH];
#pragma unroll
      for (int i = 0; i < 2; ++i)
        af[i] = *(const s16x8*)(As + abase[i] + (((c ^ asw[i])) << 3));
#pragma unroll
      for (int j = 0; j < NH; ++j)
        bfv[j] = *(const s16x8*)(Bs + bbase[j] + (((c ^ bsw[j])) << 3));
#pragma unroll
      for (int i = 0; i < 2; ++i)
#pragma unroll
        for (int j = 0; j < NH; ++j)
          acc[i][j] = __builtin_amdgcn_mfma_f32_32x32x16_bf16(
              af[i], bfv[j], acc[i][j], 0, 0, 0);
    }
    __syncthreads();
  }

  // C/D layout 32x32: col = lane&31, row = (r&3)+8*(r>>2)+4*(lane>>5)
  if constexpr (SUML) {
    __shared__ float ssum[BN];
    if (t < BN) ssum[t] = 0.f;
    __syncthreads();
#pragma unroll
    for (int j = 0; j < NH; ++j) {
      const int lcol = (wave & 1) * (BN / 2) + j * 32 + ln;
      float bj = HAS_BIAS ? bias[n0 + lcol] : 0.f;
      float part = 0.f;
#pragma unroll
      for (int i = 0; i < 2; ++i)
#pragma unroll
        for (int r = 0; r < 16; ++r) {
          float x = acc[i][j][r] + bj;
          if (RELU) x = fmaxf(x, 0.f);
          part += x;
        }
      atomicAdd(&ssum[lcol], part);
    }
    __syncthreads();
    if (t < BN) {
      const int split = (int)sC;
      int rb2 = m0 >> 8;
      const int side = rb2 >= split;
      rb2 -= side * split;
      atomicAdd((float*)Cv + (long)rb2 * ldc + side * (ldc >> 1) + n0 + t,
                ssum[t]);
    }
  } else {
#pragma unroll
    for (int j = 0; j < NH; ++j) {
      const int col = n0 + (wave & 1) * (BN / 2) + j * 32 + ln;
      float bj = 0.f;
      if (HAS_BIAS) bj = bias[col];
#pragma unroll
      for (int i = 0; i < 2; ++i) {
        const int rowb = m0 + (wave >> 1) * 64 + i * 32 + 4 * hi;
#pragma unroll
        for (int r = 0; r < 16; ++r) {
          const int row = rowb + (r & 3) + 8 * (r >> 2);
          float x = acc[i][j][r] + bj;
          if (RELU) x = fmaxf(x, 0.f);
          const long idx = (long)row * ldc + col + zb * sC;
          if (OUT_BF16)
            ((__hip_bfloat16*)Cv)[idx] = __float2bfloat16(x);
          else
            ((float*)Cv)[idx] = x;
        }
      }
    }
    if constexpr (CONCAT) {
      // Coalesced concat fill: block's 128xBN fp32 tile of sent -> bf16 right
      // half of CC. float4 reads, ushort4 writes.
      constexpr int F4 = BN / 4;  // float4s per row
      const int side = (int)(zb >= (long)cBh);
      const int bb = (int)zb - side * cBh;
      const float* csrc = side ? cs2 : cs1;
      const long crowbase = (long)bb * 256;
      __hip_bfloat16* Cb = (__hip_bfloat16*)Cv + zb * sC + 512 + n0;
#pragma unroll
      for (int k = 0; k < BN / 8; ++k) {
        const int idx = k * 256 + t;
        const int r = idx / F4;
        const int q = idx % F4;
        const float4 v =
            *(const float4*)(csrc + (crowbase + m0 + r) * 512 + n0 + q * 4);
        union {
          ushort4 u;
          __hip_bfloat16 h[4];
        } pk;
        pk.h[0] = __float2bfloat16(v.x);
        pk.h[1] = __float2bfloat16(v.y);
        pk.h[2] = __float2bfloat16(v.z);
        pk.h[3] = __float2bfloat16(v.w);
        *(ushort4*)(Cb + (long)(m0 + r) * ldc + q * 4) = pk.u;
      }
    }
  }
}

// ---------------- helpers ----------------
struct CastArgs {
  const float* src[6];
  __hip_bfloat16* dst[6];
  long n[6];
};
__global__ void cast_many(CastArgs a) {
  const int w = blockIdx.y;
  long i = ((long)blockIdx.x * blockDim.x + threadIdx.x) * 4;
  if (i >= a.n[w]) return;
  float4 v = *(const float4*)(a.src[w] + i);
  __hip_bfloat16* o = a.dst[w] + i;
  o[0] = __float2bfloat16(v.x);
  o[1] = __float2bfloat16(v.y);
  o[2] = __float2bfloat16(v.z);
  o[3] = __float2bfloat16(v.w);
}

__global__ void cast_bf16(const float* __restrict__ in,
                          __hip_bfloat16* __restrict__ out, long n) {
  long i = ((long)blockIdx.x * blockDim.x + threadIdx.x) * 4;
  if (i >= n) return;
  float4 v = *(const float4*)(in + i);
  out[i + 0] = __float2bfloat16(v.x);
  out[i + 1] = __float2bfloat16(v.y);
  out[i + 2] = __float2bfloat16(v.z);
  out[i + 3] = __float2bfloat16(v.w);
}

// Fused sent prep: fp32 sent -> row-major bf16 (S12b) AND transposed bf16
// (ST = [S2T|S1T]). z < Bh -> sent1, else sent2.
__global__ void prep_sent(const float* __restrict__ s1,
                          const float* __restrict__ s2,
                          __hip_bfloat16* __restrict__ S12b,
                          __hip_bfloat16* __restrict__ STbase, int Bh) {
  __shared__ float tile[32][33];
  const int z = blockIdx.z;
  const int e0 = blockIdx.x * 32;
  const int l0 = blockIdx.y * 32;
  const int side = z >= Bh;
  const int b = z - side * Bh;
  const float* ib = (side ? s2 : s1) + (long)b * 131072;
  __hip_bfloat16* on = S12b + (long)z * 131072;
  __hip_bfloat16* ot = STbase + (long)(side ? b : (Bh + b)) * 131072;
  const int tx = threadIdx.x, ty = threadIdx.y;
#pragma unroll
  for (int k = 0; k < 4; ++k) {
    const int l = l0 + ty + 8 * k;
    const float v = ib[(long)l * 512 + e0 + tx];
    on[(long)l * 512 + e0 + tx] = __float2bfloat16(v);
    tile[ty + 8 * k][tx] = v;
  }
  __syncthreads();
#pragma unroll
  for (int k = 0; k < 4; ++k)
    ot[(long)(e0 + ty + 8 * k) * 256 + l0 + tx] =
        __float2bfloat16(tile[tx][ty + 8 * k]);
}

// row softmax over 256 cols: E fp32 [rows][256] -> W bf16 (coalesced)
__global__ void softmax_rows(const float* __restrict__ E,
                             __hip_bfloat16* __restrict__ W) {
  const long row = blockIdx.x;
  const int t = threadIdx.x;
  const float x = E[row * 256 + t];
  float m = x;
  for (int o = 32; o > 0; o >>= 1) m = fmaxf(m, __shfl_xor(m, o));
  __shared__ float red[4];
  if ((t & 63) == 0) red[t >> 6] = m;
  __syncthreads();
  m = fmaxf(fmaxf(red[0], red[1]), fmaxf(red[2], red[3]));
  const float pr = __expf(x - m);
  float s = pr;
  for (int o = 32; o > 0; o >>= 1) s += __shfl_xor(s, o);
  __shared__ float red2[4];
  if ((t & 63) == 0) red2[t >> 6] = s;
  __syncthreads();
  s = red2[0] + red2[1] + red2[2] + red2[3];
  W[row * 256 + t] = __float2bfloat16(pr / s);
}

// Fused column softmax: strip in LDS, stats, transposed coalesced write.
__global__ __launch_bounds__(256) void softmax_cols_f(
    const float* __restrict__ E, __hip_bfloat16* __restrict__ W) {
  __shared__ float tile[256][65];
  __shared__ float mred[4][64], sred[4][64];
  const int b = blockIdx.y;
  const int j0 = blockIdx.x * 64;
  const int t = threadIdx.x;
  const int jl = t & 63, s = t >> 6;
  const float* Eb = E + (long)b * 65536 + j0;
#pragma unroll
  for (int k = 0; k < 64; ++k) {
    const int i = k * 4 + s;
    tile[i][jl] = Eb[(long)i * 256 + jl];
  }
  __syncthreads();
  float m = -3.4e38f;
#pragma unroll 8
  for (int r = 0; r < 64; ++r) m = fmaxf(m, tile[s * 64 + r][jl]);
  mred[s][jl] = m;
  __syncthreads();
  m = fmaxf(fmaxf(mred[0][jl], mred[1][jl]), fmaxf(mred[2][jl], mred[3][jl]));
  float sum = 0.f;
#pragma unroll 8
  for (int r = 0; r < 64; ++r) sum += __expf(tile[s * 64 + r][jl] - m);
  sred[s][jl] = sum;
  __syncthreads();
  const int jw = t >> 2;
  const int ib = t & 3;
  const float mj = fmaxf(fmaxf(mred[0][jw], mred[1][jw]),
                         fmaxf(mred[2][jw], mred[3][jw]));
  const float isj =
      1.0f / (sred[0][jw] + sred[1][jw] + sred[2][jw] + sred[3][jw]);
  __hip_bfloat16* Wb = W + (long)b * 65536 + (long)(j0 + jw) * 256 + ib * 64;
#pragma unroll 8
  for (int r = 0; r < 64; ++r)
    Wb[r] = __float2bfloat16(__expf(tile[ib * 64 + r][jw] - mj) * isj);
}

// out[b][o] = sum_h h2[b][h]*fin_w[o][h] + fin_b[o]
__global__ void final_lin(const __hip_bfloat16* __restrict__ h2,
                          const float* __restrict__ w,
                          const float* __restrict__ bs,
                          float* __restrict__ out) {
  const int b = blockIdx.x;
  const int t = threadIdx.x;
  float p0 = 0.f, p1 = 0.f, p2 = 0.f;
  for (int k = t; k < 1024; k += 256) {
    const float x = __bfloat162float(h2[(long)b * 1024 + k]);
    p0 += x * w[k];
    p1 += x * w[1024 + k];
    p2 += x * w[2048 + k];
  }
  for (int o = 32; o > 0; o >>= 1) {
    p0 += __shfl_xor(p0, o);
    p1 += __shfl_xor(p1, o);
    p2 += __shfl_xor(p2, o);
  }
  __shared__ float r[4][3];
  if ((t & 63) == 0) {
    r[t >> 6][0] = p0;
    r[t >> 6][1] = p1;
    r[t >> 6][2] = p2;
  }
  __syncthreads();
  if (t < 3)
    out[b * 3 + t] = r[0][t] + r[1][t] + r[2][t] + r[3][t] + bs[t];
}

extern "C" void kernel_launch(void* const* d_in, const int* in_sizes, int n_in,
                              void* d_out, int out_size, void* d_ws,
                              size_t ws_size, hipStream_t stream) {
  const float* sent1 = (const float*)d_in[0];
  const float* sent2 = (const float*)d_in[1];
  const float* f_w1 = (const float*)d_in[2];
  const float* f_b1 = (const float*)d_in[3];
  const float* f_w2 = (const float*)d_in[4];
  const float* f_b2 = (const float*)d_in[5];
  const float* g_w1 = (const float*)d_in[6];
  const float* g_b1 = (const float*)d_in[7];
  const float* g_w2 = (const float*)d_in[8];
  const float* g_b2 = (const float*)d_in[9];
  const float* h_w1 = (const float*)d_in[10];
  const float* h_b1 = (const float*)d_in[11];
  const float* h_w2 = (const float*)d_in[12];
  const float* h_b2 = (const float*)d_in[13];
  const float* fin_w = (const float*)d_in[14];
  const float* fin_b = (const float*)d_in[15];

  char* p = (char*)d_ws;
  auto take = [&](size_t n) {
    char* r = p;
    p += (n + 255) & ~(size_t)255;
    return r;
  };
  const int Bh = (ws_size >= (size_t)220 * 1024 * 1024) ? 64 : 32;
  const int chunks = 128 / Bh;
  const long R = (long)Bh * 256;

  short* Wf1 = (short*)take(1024L * 512 * 2);
  short* Wf2 = (short*)take(1024L * 1024 * 2);
  short* Wg1 = (short*)take(1024L * 1024 * 2);
  short* Wg2 = (short*)take(1024L * 1024 * 2);
  short* Wh1 = (short*)take(1024L * 2048 * 2);
  short* Wh2 = (short*)take(1024L * 1024 * 2);
  float* SUMF = (float*)take(128L * 2048 * 4);
  short* scat = (short*)take(128L * 2048 * 2);
  short* hh = (short*)take(128L * 1024 * 2);
  short* hf = (short*)take(128L * 1024 * 2);
  char* Areg = take(2 * R * 1024 * 2);  // FHID -> GHID
  char* Breg = take(2 * R * 1024 * 2);  // F12 -> CC12
  char* Creg = take(2 * R * 512 * 2);   // S12b -> E1|W1A|W2A
  char* Dreg = take(2 * R * 512 * 2);   // [S2T | S1T]
  (void)in_sizes; (void)n_in; (void)out_size;

  short* FHID = (short*)Areg;
  short* GHID = (short*)Areg;
  short* F12 = (short*)Breg;
  short* CC12 = (short*)Breg;
  short* S12b = (short*)Creg;
  float* E1 = (float*)Creg;
  short* W1A = (short*)(Creg + (long)Bh * 262144);
  short* W2A = W1A + (long)Bh * 65536;
  short* ST = (short*)Dreg;

  hipMemsetAsync(SUMF, 0, 128L * 2048 * 4, stream);

  CastArgs ca;
  ca.src[0] = f_w1; ca.dst[0] = (__hip_bfloat16*)Wf1; ca.n[0] = 524288;
  ca.src[1] = f_w2; ca.dst[1] = (__hip_bfloat16*)Wf2; ca.n[1] = 1048576;
  ca.src[2] = g_w1; ca.dst[2] = (__hip_bfloat16*)Wg1; ca.n[2] = 1048576;
  ca.src[3] = g_w2; ca.dst[3] = (__hip_bfloat16*)Wg2; ca.n[3] = 1048576;
  ca.src[4] = h_w1; ca.dst[4] = (__hip_bfloat16*)Wh1; ca.n[4] = 2097152;
  ca.src[5] = h_w2; ca.dst[5] = (__hip_bfloat16*)Wh2; ca.n[5] = 1048576;
  cast_many<<<dim3(2048, 6), 256, 0, stream>>>(ca);

  for (int c = 0; c < chunks; ++c) {
    const float* s1 = sent1 + (long)c * R * 512;
    const float* s2 = sent2 + (long)c * R * 512;
    float* SUMF_c = SUMF + (long)c * Bh * 2048;
    const int MT = (int)(2 * R / 128);

    prep_sent<<<dim3(16, 8, 2 * Bh), dim3(32, 8), 0, stream>>>(
        s1, s2, (__hip_bfloat16*)S12b, (__hip_bfloat16*)ST, Bh);

    // ---- attend MLP f (merged sides, M = 2R) ----
    gemm_nt<128, true, true, true, false, false>
        <<<dim3(8, MT, 1), 256, 0, stream>>>(S12b, Wf1, f_b1, FHID, 512, 512,
                                             512, 1024, 0, 0, 0, nullptr,
                                             nullptr, 0);
    gemm_nt<128, true, true, true, false, false>
        <<<dim3(8, MT, 1), 256, 0, stream>>>(FHID, Wf2, f_b2, F12, 1024, 1024,
                                             1024, 1024, 0, 0, 0, nullptr,
                                             nullptr, 0);

    // ---- e1 = F1 F2^T (batched fp32; overwrites S12b region; BN=64) ----
    gemm_nt<64, false, false, false, false, false>
        <<<dim3(4, 2, Bh), 256, 0, stream>>>(F12, F12 + R * 1024, nullptr, E1,
                                             1024, 1024, 1024, 256, 256L * 1024,
                                             256L * 1024, 65536, nullptr,
                                             nullptr, 0);

    // ---- softmaxes ----
    softmax_rows<<<Bh * 256, 256, 0, stream>>>(E1, (__hip_bfloat16*)W1A);
    softmax_cols_f<<<dim3(4, Bh), 256, 0, stream>>>(E1, (__hip_bfloat16*)W2A);

    // ---- att (merged, BN=64) + fused coalesced concat right-half fill ----
    gemm_nt<64, false, true, false, false, true>
        <<<dim3(8, 2, 2 * Bh), 256, 0, stream>>>(W1A, ST, nullptr, CC12, 256,
                                                 256, 256, 1024, 65536, 131072,
                                                 262144, s1, s2, Bh);

    // ---- compare MLP g (merged); layer2 accumulates sum-over-L ----
    gemm_nt<128, true, true, true, false, false>
        <<<dim3(8, MT, 1), 256, 0, stream>>>(CC12, Wg1, g_b1, GHID, 1024, 1024,
                                             1024, 1024, 0, 0, 0, nullptr,
                                             nullptr, 0);
    gemm_nt<128, true, false, true, true, false>
        <<<dim3(8, MT, 1), 256, 0, stream>>>(GHID, Wg2, g_b2, SUMF_c, 1024,
                                             1024, 1024, 2048, 0, 0, Bh,
                                             nullptr, nullptr, 0);
  }

  // ---- aggregate MLP h + final linear (BN=64) ----
  cast_bf16<<<256, 256, 0, stream>>>(SUMF, (__hip_bfloat16*)scat, 262144);
  gemm_nt<64, true, true, true, false, false><<<dim3(16, 1, 1), 256, 0, stream>>>(
      scat, Wh1, h_b1, hh, 2048, 2048, 2048, 1024, 0, 0, 0, nullptr, nullptr, 0);
  gemm_nt<64, true, true, true, false, false><<<dim3(16, 1, 1), 256, 0, stream>>>(
      hh, Wh2, h_b2, hf, 1024, 1024, 1024, 1024, 0, 0, 0, nullptr, nullptr, 0);
  final_lin<<<128, 256, 0, stream>>>((__hip_bfloat16*)hf, fin_w, fin_b,
                                     (float*)d_out);
}

// Round 11
// 931.018 us; speedup vs baseline: 1.0567x; 1.0567x over previous
//
#include <hip/hip_runtime.h>
#include <hip/hip_bf16.h>

// Decomposable attention, bf16-MFMA pipeline, chunked (Bh per side per chunk).
// R11: R10 (16x16x32 BK=64 GEMM, BN-templated) with the att GEMM grid fixed:
// att has N=512, so BN=64 needs gridDim.x=8 (R10's =4 left cols 256..511
// unwritten -> absmax 602). All fragment/staging math unchanged from R8.

using f32x4 = __attribute__((ext_vector_type(4))) float;
using s16x8 = __attribute__((ext_vector_type(8))) short;

__device__ __forceinline__ void gload_lds16(const short* g, short* l) {
  __builtin_amdgcn_global_load_lds(
      (const __attribute__((address_space(1))) unsigned int*)g,
      (__attribute__((address_space(3))) unsigned int*)l, 16, 0, 0);
}

// ---------------- GEMM: C[M,N] = A[M,K] * B[N,K]^T (+bias, relu) ----------------
// grid = (N/BN, M/128, batch), block = 256. K % 64 == 0.
// LDS: [rows][64] bf16; row r chunk c (16B) at slot c ^ (r&7); fragment read
// offset ^ (kk*32) flips chunk bit2 for the k-upper half (R8 layout, 0 confl).
// SUML (BN=128 only): row-sum per 256-row batch into float Cv; sC = split.
// CONCAT: att epilogue fills right concat half (coalesced tile sweep).
template <int BN, bool RELU, bool OUT_BF16, bool HAS_BIAS, bool SUML,
          bool CONCAT>
__global__ __launch_bounds__(256, 4) void gemm_nt(
    const short* __restrict__ A, const short* __restrict__ B,
    const float* __restrict__ bias, void* __restrict__ Cv, int K, int lda,
    int ldb, int ldc, long sA, long sB, long sC, const float* __restrict__ cs1,
    const float* __restrict__ cs2, int cBh) {
  constexpr int NJ = BN / 32;  // 16-col frags per wave (4 for BN=128, 2 for 64)
  __shared__ __align__(16) short As[128 * 64];
  __shared__ __align__(16) short Bs[BN * 64];
  const int t = threadIdx.x;
  const int lane = t & 63;
  const int wave = t >> 6;

  // XCD-aware swizzle (flat%8 ~ XCD): contiguous tile range per XCD.
  unsigned flat = (blockIdx.z * gridDim.y + blockIdx.y) * gridDim.x + blockIdx.x;
  const unsigned total = gridDim.x * gridDim.y * gridDim.z;
  unsigned bx = blockIdx.x, by = blockIdx.y, bz = blockIdx.z;
  if ((total & 7u) == 0) {
    unsigned nf = (flat & 7u) * (total >> 3) + (flat >> 3);
    bx = nf % gridDim.x;
    unsigned rest = nf / gridDim.x;
    by = rest % gridDim.y;
    bz = rest / gridDim.y;
  }
  const int m0 = by * 128;
  const int n0 = bx * BN;
  const long zb = bz;

  // staging: issue q covers 32 rows; thread t -> row q*32+(t>>3), slot (t&7),
  // fetching global chunk (t&7)^(row&7).
  const int srow = t >> 3;
  const int schunk = ((t & 7) ^ (srow & 7)) * 8;
  const short* ag = A + zb * sA + (long)(m0 + srow) * lda + schunk;
  const short* bg = B + zb * sB + (long)(n0 + srow) * ldb + schunk;
  const long a32 = (long)32 * lda, b32 = (long)32 * ldb;
  short* AsW = As + wave * 512;
  short* BsW = Bs + wave * 512;

  const int fr = lane & 15;
  const int kq = lane >> 4;  // 16B chunk (k-lower half) 0..3
  int aoff[4], boff[NJ];
#pragma unroll
  for (int i = 0; i < 4; ++i) {
    const int ra = (wave >> 1) * 64 + i * 16 + fr;
    aoff[i] = ra * 64 + ((kq ^ (ra & 7)) * 8);
  }
#pragma unroll
  for (int j = 0; j < NJ; ++j) {
    const int rb = (wave & 1) * (BN / 2) + j * 16 + fr;
    boff[j] = rb * 64 + ((kq ^ (rb & 7)) * 8);
  }

  f32x4 acc[4][NJ] = {};

  for (int it = K >> 6; it > 0; --it) {
    gload_lds16(ag, AsW);
    gload_lds16(ag + a32, AsW + 2048);
    gload_lds16(ag + 2 * a32, AsW + 4096);
    gload_lds16(ag + 3 * a32, AsW + 6144);
#pragma unroll
    for (int q = 0; q < BN / 32; ++q)
      gload_lds16(bg + q * b32, BsW + q * 2048);
    ag += 64;
    bg += 64;
    __syncthreads();
#pragma unroll
    for (int kk = 0; kk < 2; ++kk) {
      const int x = kk * 32;  // ^32 flips chunk bit2 -> k-upper 16B
      s16x8 af[4], bfv[NJ];
#pragma unroll
      for (int i = 0; i < 4; ++i) af[i] = *(const s16x8*)(As + (aoff[i] ^ x));
#pragma unroll
      for (int j = 0; j < NJ; ++j) bfv[j] = *(const s16x8*)(Bs + (boff[j] ^ x));
#pragma unroll
      for (int i = 0; i < 4; ++i)
#pragma unroll
        for (int j = 0; j < NJ; ++j)
          acc[i][j] = __builtin_amdgcn_mfma_f32_16x16x32_bf16(
              af[i], bfv[j], acc[i][j], 0, 0, 0);
    }
    __syncthreads();
  }

  // C/D layout: col = lane&15, row = (lane>>4)*4 + reg  [m89/m91-verified]
  const int ccol = lane & 15;
  const int crow = (lane >> 4) * 4;

  if constexpr (SUML) {
    __shared__ float ssum[BN];
    if (t < BN) ssum[t] = 0.f;
    __syncthreads();
#pragma unroll
    for (int j = 0; j < NJ; ++j) {
      const int lcol = (wave & 1) * (BN / 2) + j * 16 + ccol;
      float bj = HAS_BIAS ? bias[n0 + lcol] : 0.f;
      float part = 0.f;
#pragma unroll
      for (int i = 0; i < 4; ++i)
#pragma unroll
        for (int r = 0; r < 4; ++r) {
          float x = acc[i][j][r] + bj;
          if (RELU) x = fmaxf(x, 0.f);
          part += x;
        }
      atomicAdd(&ssum[lcol], part);
    }
    __syncthreads();
    if (t < BN) {
      const int split = (int)sC;
      int rb2 = m0 >> 8;
      const int side = rb2 >= split;
      rb2 -= side * split;
      atomicAdd((float*)Cv + (long)rb2 * ldc + side * (ldc >> 1) + n0 + t,
                ssum[t]);
    }
  } else {
#pragma unroll
    for (int j = 0; j < NJ; ++j) {
      const int col = n0 + (wave & 1) * (BN / 2) + j * 16 + ccol;
      float bj = 0.f;
      if (HAS_BIAS) bj = bias[col];
#pragma unroll
      for (int i = 0; i < 4; ++i) {
        const int row0 = m0 + (wave >> 1) * 64 + i * 16 + crow;
#pragma unroll
        for (int r = 0; r < 4; ++r) {
          float x = acc[i][j][r] + bj;
          if (RELU) x = fmaxf(x, 0.f);
          const long idx = (long)(row0 + r) * ldc + col + zb * sC;
          if (OUT_BF16)
            ((__hip_bfloat16*)Cv)[idx] = __float2bfloat16(x);
          else
            ((float*)Cv)[idx] = x;
        }
      }
    }
    if constexpr (CONCAT) {
      // Coalesced concat fill: block's 128xBN fp32 tile of sent -> bf16 right
      // half of CC. float4 reads, ushort4 writes.
      constexpr int F4 = BN / 4;  // float4s per row
      const int side = (int)(zb >= (long)cBh);
      const int bb = (int)zb - side * cBh;
      const float* csrc = side ? cs2 : cs1;
      const long crowbase = (long)bb * 256;
      __hip_bfloat16* Cb = (__hip_bfloat16*)Cv + zb * sC + 512 + n0;
#pragma unroll
      for (int k = 0; k < BN / 8; ++k) {
        const int idx = k * 256 + t;
        const int r = idx / F4;
        const int q = idx % F4;
        const float4 v =
            *(const float4*)(csrc + (crowbase + m0 + r) * 512 + n0 + q * 4);
        union {
          ushort4 u;
          __hip_bfloat16 h[4];
        } pk;
        pk.h[0] = __float2bfloat16(v.x);
        pk.h[1] = __float2bfloat16(v.y);
        pk.h[2] = __float2bfloat16(v.z);
        pk.h[3] = __float2bfloat16(v.w);
        *(ushort4*)(Cb + (long)(m0 + r) * ldc + q * 4) = pk.u;
      }
    }
  }
}

// ---------------- helpers ----------------
struct CastArgs {
  const float* src[6];
  __hip_bfloat16* dst[6];
  long n[6];
};
__global__ void cast_many(CastArgs a) {
  const int w = blockIdx.y;
  long i = ((long)blockIdx.x * blockDim.x + threadIdx.x) * 4;
  if (i >= a.n[w]) return;
  float4 v = *(const float4*)(a.src[w] + i);
  __hip_bfloat16* o = a.dst[w] + i;
  o[0] = __float2bfloat16(v.x);
  o[1] = __float2bfloat16(v.y);
  o[2] = __float2bfloat16(v.z);
  o[3] = __float2bfloat16(v.w);
}

__global__ void cast_bf16(const float* __restrict__ in,
                          __hip_bfloat16* __restrict__ out, long n) {
  long i = ((long)blockIdx.x * blockDim.x + threadIdx.x) * 4;
  if (i >= n) return;
  float4 v = *(const float4*)(in + i);
  out[i + 0] = __float2bfloat16(v.x);
  out[i + 1] = __float2bfloat16(v.y);
  out[i + 2] = __float2bfloat16(v.z);
  out[i + 3] = __float2bfloat16(v.w);
}

// Fused sent prep: fp32 sent -> row-major bf16 (S12b) AND transposed bf16
// (ST = [S2T|S1T]). z < Bh -> sent1, else sent2.
__global__ void prep_sent(const float* __restrict__ s1,
                          const float* __restrict__ s2,
                          __hip_bfloat16* __restrict__ S12b,
                          __hip_bfloat16* __restrict__ STbase, int Bh) {
  __shared__ float tile[32][33];
  const int z = blockIdx.z;
  const int e0 = blockIdx.x * 32;
  const int l0 = blockIdx.y * 32;
  const int side = z >= Bh;
  const int b = z - side * Bh;
  const float* ib = (side ? s2 : s1) + (long)b * 131072;
  __hip_bfloat16* on = S12b + (long)z * 131072;
  __hip_bfloat16* ot = STbase + (long)(side ? b : (Bh + b)) * 131072;
  const int tx = threadIdx.x, ty = threadIdx.y;
#pragma unroll
  for (int k = 0; k < 4; ++k) {
    const int l = l0 + ty + 8 * k;
    const float v = ib[(long)l * 512 + e0 + tx];
    on[(long)l * 512 + e0 + tx] = __float2bfloat16(v);
    tile[ty + 8 * k][tx] = v;
  }
  __syncthreads();
#pragma unroll
  for (int k = 0; k < 4; ++k)
    ot[(long)(e0 + ty + 8 * k) * 256 + l0 + tx] =
        __float2bfloat16(tile[tx][ty + 8 * k]);
}

// row softmax over 256 cols: E fp32 [rows][256] -> W bf16 (coalesced)
__global__ void softmax_rows(const float* __restrict__ E,
                             __hip_bfloat16* __restrict__ W) {
  const long row = blockIdx.x;
  const int t = threadIdx.x;
  const float x = E[row * 256 + t];
  float m = x;
  for (int o = 32; o > 0; o >>= 1) m = fmaxf(m, __shfl_xor(m, o));
  __shared__ float red[4];
  if ((t & 63) == 0) red[t >> 6] = m;
  __syncthreads();
  m = fmaxf(fmaxf(red[0], red[1]), fmaxf(red[2], red[3]));
  const float pr = __expf(x - m);
  float s = pr;
  for (int o = 32; o > 0; o >>= 1) s += __shfl_xor(s, o);
  __shared__ float red2[4];
  if ((t & 63) == 0) red2[t >> 6] = s;
  __syncthreads();
  s = red2[0] + red2[1] + red2[2] + red2[3];
  W[row * 256 + t] = __float2bfloat16(pr / s);
}

// Fused column softmax: strip in LDS, stats, transposed coalesced write.
__global__ __launch_bounds__(256) void softmax_cols_f(
    const float* __restrict__ E, __hip_bfloat16* __restrict__ W) {
  __shared__ float tile[256][65];
  __shared__ float mred[4][64], sred[4][64];
  const int b = blockIdx.y;
  const int j0 = blockIdx.x * 64;
  const int t = threadIdx.x;
  const int jl = t & 63, s = t >> 6;
  const float* Eb = E + (long)b * 65536 + j0;
#pragma unroll
  for (int k = 0; k < 64; ++k) {
    const int i = k * 4 + s;
    tile[i][jl] = Eb[(long)i * 256 + jl];
  }
  __syncthreads();
  float m = -3.4e38f;
#pragma unroll 8
  for (int r = 0; r < 64; ++r) m = fmaxf(m, tile[s * 64 + r][jl]);
  mred[s][jl] = m;
  __syncthreads();
  m = fmaxf(fmaxf(mred[0][jl], mred[1][jl]), fmaxf(mred[2][jl], mred[3][jl]));
  float sum = 0.f;
#pragma unroll 8
  for (int r = 0; r < 64; ++r) sum += __expf(tile[s * 64 + r][jl] - m);
  sred[s][jl] = sum;
  __syncthreads();
  const int jw = t >> 2;
  const int ib = t & 3;
  const float mj = fmaxf(fmaxf(mred[0][jw], mred[1][jw]),
                         fmaxf(mred[2][jw], mred[3][jw]));
  const float isj =
      1.0f / (sred[0][jw] + sred[1][jw] + sred[2][jw] + sred[3][jw]);
  __hip_bfloat16* Wb = W + (long)b * 65536 + (long)(j0 + jw) * 256 + ib * 64;
#pragma unroll 8
  for (int r = 0; r < 64; ++r)
    Wb[r] = __float2bfloat16(__expf(tile[ib * 64 + r][jw] - mj) * isj);
}

// out[b][o] = sum_h h2[b][h]*fin_w[o][h] + fin_b[o]
__global__ void final_lin(const __hip_bfloat16* __restrict__ h2,
                          const float* __restrict__ w,
                          const float* __restrict__ bs,
                          float* __restrict__ out) {
  const int b = blockIdx.x;
  const int t = threadIdx.x;
  float p0 = 0.f, p1 = 0.f, p2 = 0.f;
  for (int k = t; k < 1024; k += 256) {
    const float x = __bfloat162float(h2[(long)b * 1024 + k]);
    p0 += x * w[k];
    p1 += x * w[1024 + k];
    p2 += x * w[2048 + k];
  }
  for (int o = 32; o > 0; o >>= 1) {
    p0 += __shfl_xor(p0, o);
    p1 += __shfl_xor(p1, o);
    p2 += __shfl_xor(p2, o);
  }
  __shared__ float r[4][3];
  if ((t & 63) == 0) {
    r[t >> 6][0] = p0;
    r[t >> 6][1] = p1;
    r[t >> 6][2] = p2;
  }
  __syncthreads();
  if (t < 3)
    out[b * 3 + t] = r[0][t] + r[1][t] + r[2][t] + r[3][t] + bs[t];
}

extern "C" void kernel_launch(void* const* d_in, const int* in_sizes, int n_in,
                              void* d_out, int out_size, void* d_ws,
                              size_t ws_size, hipStream_t stream) {
  const float* sent1 = (const float*)d_in[0];
  const float* sent2 = (const float*)d_in[1];
  const float* f_w1 = (const float*)d_in[2];
  const float* f_b1 = (const float*)d_in[3];
  const float* f_w2 = (const float*)d_in[4];
  const float* f_b2 = (const float*)d_in[5];
  const float* g_w1 = (const float*)d_in[6];
  const float* g_b1 = (const float*)d_in[7];
  const float* g_w2 = (const float*)d_in[8];
  const float* g_b2 = (const float*)d_in[9];
  const float* h_w1 = (const float*)d_in[10];
  const float* h_b1 = (const float*)d_in[11];
  const float* h_w2 = (const float*)d_in[12];
  const float* h_b2 = (const float*)d_in[13];
  const float* fin_w = (const float*)d_in[14];
  const float* fin_b = (const float*)d_in[15];

  char* p = (char*)d_ws;
  auto take = [&](size_t n) {
    char* r = p;
    p += (n + 255) & ~(size_t)255;
    return r;
  };
  const int Bh = (ws_size >= (size_t)220 * 1024 * 1024) ? 64 : 32;
  const int chunks = 128 / Bh;
  const long R = (long)Bh * 256;

  short* Wf1 = (short*)take(1024L * 512 * 2);
  short* Wf2 = (short*)take(1024L * 1024 * 2);
  short* Wg1 = (short*)take(1024L * 1024 * 2);
  short* Wg2 = (short*)take(1024L * 1024 * 2);
  short* Wh1 = (short*)take(1024L * 2048 * 2);
  short* Wh2 = (short*)take(1024L * 1024 * 2);
  float* SUMF = (float*)take(128L * 2048 * 4);
  short* scat = (short*)take(128L * 2048 * 2);
  short* hh = (short*)take(128L * 1024 * 2);
  short* hf = (short*)take(128L * 1024 * 2);
  char* Areg = take(2 * R * 1024 * 2);  // FHID -> GHID
  char* Breg = take(2 * R * 1024 * 2);  // F12 -> CC12
  char* Creg = take(2 * R * 512 * 2);   // S12b -> E1|W1A|W2A
  char* Dreg = take(2 * R * 512 * 2);   // [S2T | S1T]
  (void)in_sizes; (void)n_in; (void)out_size;

  short* FHID = (short*)Areg;
  short* GHID = (short*)Areg;
  short* F12 = (short*)Breg;
  short* CC12 = (short*)Breg;
  short* S12b = (short*)Creg;
  float* E1 = (float*)Creg;
  short* W1A = (short*)(Creg + (long)Bh * 262144);
  short* W2A = W1A + (long)Bh * 65536;
  short* ST = (short*)Dreg;

  hipMemsetAsync(SUMF, 0, 128L * 2048 * 4, stream);

  CastArgs ca;
  ca.src[0] = f_w1; ca.dst[0] = (__hip_bfloat16*)Wf1; ca.n[0] = 524288;
  ca.src[1] = f_w2; ca.dst[1] = (__hip_bfloat16*)Wf2; ca.n[1] = 1048576;
  ca.src[2] = g_w1; ca.dst[2] = (__hip_bfloat16*)Wg1; ca.n[2] = 1048576;
  ca.src[3] = g_w2; ca.dst[3] = (__hip_bfloat16*)Wg2; ca.n[3] = 1048576;
  ca.src[4] = h_w1; ca.dst[4] = (__hip_bfloat16*)Wh1; ca.n[4] = 2097152;
  ca.src[5] = h_w2; ca.dst[5] = (__hip_bfloat16*)Wh2; ca.n[5] = 1048576;
  cast_many<<<dim3(2048, 6), 256, 0, stream>>>(ca);

  for (int c = 0; c < chunks; ++c) {
    const float* s1 = sent1 + (long)c * R * 512;
    const float* s2 = sent2 + (long)c * R * 512;
    float* SUMF_c = SUMF + (long)c * Bh * 2048;
    const int MT = (int)(2 * R / 128);

    prep_sent<<<dim3(16, 8, 2 * Bh), dim3(32, 8), 0, stream>>>(
        s1, s2, (__hip_bfloat16*)S12b, (__hip_bfloat16*)ST, Bh);

    // ---- attend MLP f (merged sides, M = 2R) ----
    gemm_nt<128, true, true, true, false, false>
        <<<dim3(8, MT, 1), 256, 0, stream>>>(S12b, Wf1, f_b1, FHID, 512, 512,
                                             512, 1024, 0, 0, 0, nullptr,
                                             nullptr, 0);
    gemm_nt<128, true, true, true, false, false>
        <<<dim3(8, MT, 1), 256, 0, stream>>>(FHID, Wf2, f_b2, F12, 1024, 1024,
                                             1024, 1024, 0, 0, 0, nullptr,
                                             nullptr, 0);

    // ---- e1 = F1 F2^T (batched fp32; overwrites S12b region; BN=64, N=256) ----
    gemm_nt<64, false, false, false, false, false>
        <<<dim3(4, 2, Bh), 256, 0, stream>>>(F12, F12 + R * 1024, nullptr, E1,
                                             1024, 1024, 1024, 256, 256L * 1024,
                                             256L * 1024, 65536, nullptr,
                                             nullptr, 0);

    // ---- softmaxes ----
    softmax_rows<<<Bh * 256, 256, 0, stream>>>(E1, (__hip_bfloat16*)W1A);
    softmax_cols_f<<<dim3(4, Bh), 256, 0, stream>>>(E1, (__hip_bfloat16*)W2A);

    // ---- att (merged, BN=64, N=512 -> gridDim.x = 8) + fused concat fill ----
    gemm_nt<64, false, true, false, false, true>
        <<<dim3(8, 2, 2 * Bh), 256, 0, stream>>>(W1A, ST, nullptr, CC12, 256,
                                                 256, 256, 1024, 65536, 131072,
                                                 262144, s1, s2, Bh);

    // ---- compare MLP g (merged); layer2 accumulates sum-over-L ----
    gemm_nt<128, true, true, true, false, false>
        <<<dim3(8, MT, 1), 256, 0, stream>>>(CC12, Wg1, g_b1, GHID, 1024, 1024,
                                             1024, 1024, 0, 0, 0, nullptr,
                                             nullptr, 0);
    gemm_nt<128, true, false, true, true, false>
        <<<dim3(8, MT, 1), 256, 0, stream>>>(GHID, Wg2, g_b2, SUMF_c, 1024,
                                             1024, 1024, 2048, 0, 0, Bh,
                                             nullptr, nullptr, 0);
  }

  // ---- aggregate MLP h + final linear (BN=64) ----
  cast_bf16<<<256, 256, 0, stream>>>(SUMF, (__hip_bfloat16*)scat, 262144);
  gemm_nt<64, true, true, true, false, false><<<dim3(16, 1, 1), 256, 0, stream>>>(
      scat, Wh1, h_b1, hh, 2048, 2048, 2048, 1024, 0, 0, 0, nullptr, nullptr, 0);
  gemm_nt<64, true, true, true, false, false><<<dim3(16, 1, 1), 256, 0, stream>>>(
      hh, Wh2, h_b2, hf, 1024, 1024, 1024, 1024, 0, 0, 0, nullptr, nullptr, 0);
  final_lin<<<128, 256, 0, stream>>>((__hip_bfloat16*)hf, fin_w, fin_b,
                                     (float*)d_out);
}